// Round 13
// baseline (130.259 us; speedup 1.0000x reference)
//
#include <hip/hip_runtime.h>
#include <hip/hip_bf16.h>
#include <cmath>

#define B_N 8192
#define D_K 128
#define ROWS 128           // rows per block: 4 waves x 32 rows (one 32x32 M-tile each)
#define CSPLIT 16          // column splits; block covers 512 cols; grid 1024
#define T_OUT 8            // 64-col stages per block: 512/64

typedef short bf16x8 __attribute__((ext_vector_type(8)));
typedef unsigned short u16x8 __attribute__((ext_vector_type(8)));
typedef float f32x16 __attribute__((ext_vector_type(16)));

typedef __attribute__((address_space(3))) unsigned int as3_uint;
typedef __attribute__((address_space(1))) unsigned int as1_uint;

// Async global->LDS DMA, 16 B/lane. HW dest = wave-uniform base + lane*16
// (pattern correctness-verified R9-R12, absmax 0.0).
__device__ __forceinline__ void gl_lds16(const void* g, void* l) {
    __builtin_amdgcn_global_load_lds((const as1_uint*)(uintptr_t)g,
                                     (as3_uint*)(unsigned int)(uintptr_t)l,
                                     16, 0, 0);
}

__device__ inline unsigned short f2bf(float f) {
    unsigned u = __builtin_bit_cast(unsigned, f);
    u += 0x7fffu + ((u >> 16) & 1u);   // round-to-nearest-even
    return (unsigned short)(u >> 16);
}

// Convert fp32 Q (row-major bf16) and A (packed for 32x32x16 B-operand).
// A-pack (R11-verified): per 32-col tile N, per k-step s16 (16 k), 1 KB region at
// (N*8+s16)*1024 B; lane L = h*32+nl holds 16 B covering
// A[col=N*32+nl][k = s16*16 + h*8 .. +7] == B-op[k][n] for mfma_32x32x16.
// Also zeroes d_out (harness re-poisons to 0xAA before every replay).
__global__ void cvt_kernel(const float* __restrict__ q, const float* __restrict__ a,
                           unsigned short* __restrict__ qb, unsigned short* __restrict__ ab,
                           float* __restrict__ out) {
    int g = blockIdx.x * blockDim.x + threadIdx.x;   // 0 .. B*D/8-1
    if (g < 2) out[g] = 0.0f;
    float4 q0 = reinterpret_cast<const float4*>(q)[g * 2];
    float4 q1 = reinterpret_cast<const float4*>(q)[g * 2 + 1];
    u16x8 oq;
    oq[0] = f2bf(q0.x); oq[1] = f2bf(q0.y); oq[2] = f2bf(q0.z); oq[3] = f2bf(q0.w);
    oq[4] = f2bf(q1.x); oq[5] = f2bf(q1.y); oq[6] = f2bf(q1.z); oq[7] = f2bf(q1.w);
    *reinterpret_cast<u16x8*>(qb + (size_t)g * 8) = oq;

    float4 a0 = reinterpret_cast<const float4*>(a)[g * 2];
    float4 a1 = reinterpret_cast<const float4*>(a)[g * 2 + 1];
    u16x8 oa;
    oa[0] = f2bf(a0.x); oa[1] = f2bf(a0.y); oa[2] = f2bf(a0.z); oa[3] = f2bf(a0.w);
    oa[4] = f2bf(a1.x); oa[5] = f2bf(a1.y); oa[6] = f2bf(a1.z); oa[7] = f2bf(a1.w);
    const int col = g >> 4, sq = g & 15;           // k = sq*8 .. +7
    const int N = col >> 5, nl = col & 31;
    const int s16 = sq >> 1, h = sq & 1;
    const int lane = h * 32 + nl;
    *reinterpret_cast<u16x8*>(ab + (size_t)(N * 8 + s16) * 512 + lane * 8) = oa;
}

// Block (rg, cs): rows [rg*128,+128) over cols [cs*512,+512). 256 threads = 4
// waves; wave w owns rows [+w*32,+32) as ONE 32x32 MFMA M-tile; all 4 waves share
// each staged 16 KB B-tile -> 8 B/cell LDS traffic.
// R13 register diet (target <=128 for 4 waves/SIMD; m69: occupancy halves at
// VGPR {64,128,256}): mxp[16] -> 1-reg positive-max bitmask `flag`; qidrow[16] ->
// qpack[8] (2x16-bit, qids<2048). __launch_bounds__(256,2) kept so the compiler
// NEVER spills (graceful: >128 regs just means R12-level occupancy, not scratch).
// MFMA 32x32x16 bf16 (R1-verified, absmax 0.0):
//   A-op: lane holds A[m=lane&31][k=(lane>>5)*8+j]; B-op: B[k=(lane>>5)*8+j][n=lane&31]
//   C/D : col=lane&31, row=(reg&3)+8*(reg>>2)+4*(lane>>5)
// Sentinels: WRITE_SIZE ~2 MB, SQ_LDS_BANK_CONFLICT ~0.
__launch_bounds__(256, 2)
__global__ void mpl_part_kernel(const unsigned short* __restrict__ qb,
                                const unsigned short* __restrict__ ab,
                                const int* __restrict__ qids,
                                const float* __restrict__ ranks,
                                float* __restrict__ pden, float* __restrict__ pnum,
                                float* __restrict__ pmax, float* __restrict__ pflag) {
    __shared__ unsigned short smem[2 * 8192];   // 2 x 16 KB

    const int tid  = threadIdx.x;
    const int lane = tid & 63;
    const int wave = tid >> 6;               // 0..3
    const int rg   = blockIdx.x >> 4;        // 0..63
    const int cs   = blockIdx.x & 15;        // 0..15 (cs&7 == XCD id under %8 dispatch)
    const int waveRow = rg * ROWS + wave * 32;
    const int half = lane >> 5;              // 0 or 1
    const int l31  = lane & 31;

    // Q fragments: one 32-row tile x 8 k-steps of 16 (32 VGPRs).
    bf16x8 qfrag[8];
    {
        const unsigned short* qrow = qb + (size_t)(waveRow + l31) * D_K + half * 8;
        #pragma unroll
        for (int s = 0; s < 8; ++s)
            qfrag[s] = *reinterpret_cast<const bf16x8*>(qrow + s * 16);
    }

    // Row qids packed 2x16-bit (qids < 2048): row(r) = (r&3)+8*(r>>2)+4*half.
    unsigned qpack[8];
    #pragma unroll
    for (int i = 0; i < 8; ++i) {
        const int r0 = 2 * i, r1 = 2 * i + 1;
        const int row0 = waveRow + (r0 & 3) + 8 * (r0 >> 2) + 4 * half;
        const int row1 = waveRow + (r1 & 3) + 8 * (r1 >> 2) + 4 * half;
        qpack[i] = (unsigned)qids[row0] | ((unsigned)qids[row1] << 16);
    }

    float den[16], num[16], mxv[16];
    unsigned flag = 0u;                      // bit r: current mxv[r] attained by a positive col
    #pragma unroll
    for (int r = 0; r < 16; ++r) {
        den[r] = 0.f; num[r] = 0.f; mxv[r] = -INFINITY;
    }

    const float L2E = 1.4426950408889634f;   // log2(e)
    const float CB  = 64.0f;                 // fixed exponent bias; cancels in num/den
    const int colStart = cs * 512;

    // Packed A bytes for this block's 512-col strip: 16 N-tiles x 8 KB = 128 KB.
    const char* gstrip = (const char*)ab + (size_t)cs * 131072;
    const int   chunk  = wave * 4096;        // this wave's 4 KB of each 16 KB stage

    // Prologue: stage 0 into buffer 0.
    #pragma unroll
    for (int i = 0; i < 4; ++i)
        gl_lds16(gstrip + chunk + i * 1024 + lane * 16,
                 (char*)smem + chunk + i * 1024);
    __syncthreads();

    for (int t = 0; t < T_OUT; ++t) {
        const int cur = t & 1, nxt = cur ^ 1;
        if (t + 1 < T_OUT) {
            const char* gsrc = gstrip + (size_t)(t + 1) * 16384 + chunk;
            char*       ldst = (char*)smem + nxt * 16384 + chunk;
            #pragma unroll
            for (int i = 0; i < 4; ++i)
                gl_lds16(gsrc + i * 1024 + lane * 16, ldst + i * 1024);
        }

        const unsigned short* lbase = smem + cur * 8192 + lane * 8;
        #pragma unroll
        for (int nt = 0; nt < 2; ++nt) {
            const int c  = colStart + t * 64 + nt * 32 + l31;   // this lane's column
            const int qc = qids[c];
            const float wc = 1.0f - 0.1f * ranks[c];

            f32x16 acc;
            #pragma unroll
            for (int i = 0; i < 16; ++i) acc[i] = 0.f;
            #pragma unroll
            for (int s = 0; s < 8; ++s) {
                bf16x8 bfrag = *reinterpret_cast<const bf16x8*>(lbase + nt * 4096 + s * 512);
                acc = __builtin_amdgcn_mfma_f32_32x32x16_bf16(qfrag[s], bfrag, acc, 0, 0, 0);
            }

            #pragma unroll
            for (int r = 0; r < 16; ++r) {
                float sv = acc[r];
                float e  = __builtin_amdgcn_exp2f(fmaf(sv, L2E, -CB));
                den[r] += e;
                const int qr = (r & 1) ? (int)(qpack[r >> 1] >> 16)
                                       : (int)(qpack[r >> 1] & 0xffffu);
                const bool pos = (qc == qr);
                num[r] = fmaf(pos ? wc : 0.0f, e, num[r]);
                const bool gt = sv > mxv[r];          // strict >: first occurrence wins
                mxv[r] = gt ? sv : mxv[r];
                const unsigned bit  = 1u << r;
                const unsigned cand = (flag & ~bit) | (pos ? bit : 0u);
                flag = gt ? cand : flag;
            }
        }
        __syncthreads();   // reads of cur done + stage of nxt done
    }

    // Reduce over the 32 columns within each half (masks keep bit5 fixed).
    #pragma unroll
    for (int m = 1; m <= 16; m <<= 1) {
        const unsigned ofl = __shfl_xor(flag, m, 64);
        #pragma unroll
        for (int r = 0; r < 16; ++r) {
            den[r] += __shfl_xor(den[r], m, 64);
            num[r] += __shfl_xor(num[r], m, 64);
            const float ov = __shfl_xor(mxv[r], m, 64);
            const bool gt = ov > mxv[r];
            mxv[r] = gt ? ov : mxv[r];
            const unsigned bit = 1u << r;
            flag = gt ? ((flag & ~bit) | (ofl & bit)) : flag;
        }
    }

    if (l31 == 0) {   // lanes 0 and 32: each owns 16 of the wave's 32 rows
        #pragma unroll
        for (int r = 0; r < 16; ++r) {
            const int row = waveRow + (r & 3) + 8 * (r >> 2) + 4 * half;
            pden[cs * B_N + row]  = den[r];
            pnum[cs * B_N + row]  = num[r];
            pmax[cs * B_N + row]  = mxv[r];
            pflag[cs * B_N + row] = ((flag >> r) & 1u) ? 1.0f : 0.0f;
        }
    }
}

// Finalize: 32 blocks x 256 threads, one row per thread (coalesced partial reads),
// block-reduce, atomicAdd into d_out (zeroed by cvt_kernel).
// Accuracy: flag of the partition attaining the global row max (strict >: first
// partition wins ties, matching ascending-column first-occurrence).
__launch_bounds__(256, 4)
__global__ void fin_kernel(const float* __restrict__ pden, const float* __restrict__ pnum,
                           const float* __restrict__ pmax, const float* __restrict__ pflag,
                           float* __restrict__ out) {
    const int r = blockIdx.x * 256 + threadIdx.x;
    float d = 0.f, n = 0.f, mv = -INFINITY, fl = 0.f;
    #pragma unroll
    for (int cs = 0; cs < CSPLIT; ++cs) {
        d += pden[cs * B_N + r];
        n += pnum[cs * B_N + r];
        const float v = pmax[cs * B_N + r];
        const float f = pflag[cs * B_N + r];
        const bool gt = v > mv;
        mv = gt ? v : mv;
        fl = gt ? f : fl;
    }
    float lsum = -logf(n / d + 1e-8f);
    float csum = fl;
    #pragma unroll
    for (int m = 1; m <= 32; m <<= 1) {
        lsum += __shfl_xor(lsum, m, 64);
        csum += __shfl_xor(csum, m, 64);
    }
    __shared__ float sl[4], sc[4];
    const int wave = threadIdx.x >> 6;
    if ((threadIdx.x & 63) == 0) { sl[wave] = lsum; sc[wave] = csum; }
    __syncthreads();
    if (threadIdx.x == 0) {
        float L = sl[0] + sl[1] + sl[2] + sl[3];
        float C = sc[0] + sc[1] + sc[2] + sc[3];
        atomicAdd(&out[0], L * (1.0f / B_N));
        atomicAdd(&out[1], C * (1.0f / B_N));
    }
}

extern "C" void kernel_launch(void* const* d_in, const int* in_sizes, int n_in,
                              void* d_out, int out_size, void* d_ws, size_t ws_size,
                              hipStream_t stream) {
    const float* q     = (const float*)d_in[0];
    const float* a     = (const float*)d_in[1];
    const int*   qids  = (const int*)d_in[2];
    const float* ranks = (const float*)d_in[3];
    float* out = (float*)d_out;

    unsigned short* qb = (unsigned short*)d_ws;
    unsigned short* ab = qb + (size_t)B_N * D_K;
    char* p = (char*)(ab + (size_t)B_N * D_K);
    float* pden  = (float*)p;                p += CSPLIT * B_N * sizeof(float);
    float* pnum  = (float*)p;                p += CSPLIT * B_N * sizeof(float);
    float* pmax  = (float*)p;                p += CSPLIT * B_N * sizeof(float);
    float* pflag = (float*)p;

    cvt_kernel<<<(B_N * D_K / 8) / 256, 256, 0, stream>>>(q, a, qb, ab, out);
    mpl_part_kernel<<<(B_N / ROWS) * CSPLIT, 256, 0, stream>>>(qb, ab, qids, ranks,
                                                               pden, pnum, pmax, pflag);
    fin_kernel<<<B_N / 256, 256, 0, stream>>>(pden, pnum, pmax, pflag, out);
}

// Round 14
// 95.316 us; speedup vs baseline: 1.3666x; 1.3666x over previous
//
#include <hip/hip_runtime.h>
#include <cmath>

#define B_N 8192
#define D_K 128
#define ROWS 64            // rows per block; wave w owns rows [w*16, +16)
#define CSPLIT 8           // column splits; block covers 1024 cols
#define T_OUT 8            // 128-col super-tiles per block: 1024/128 (fp8: 16KB stage)

typedef float f32x4 __attribute__((ext_vector_type(4)));
typedef long  lx2   __attribute__((ext_vector_type(2)));

typedef __attribute__((address_space(3))) unsigned int as3_uint;
typedef __attribute__((address_space(1))) unsigned int as1_uint;

// Async global->LDS DMA, 16 B/lane. HW dest = wave-uniform base + lane*16
// (pattern correctness-verified R9-R13, absmax 0.0).
__device__ __forceinline__ void gl_lds16(const void* g, void* l) {
    __builtin_amdgcn_global_load_lds((const as1_uint*)(uintptr_t)g,
                                     (as3_uint*)(unsigned int)(uintptr_t)l,
                                     16, 0, 0);
}

// Convert fp32 Q and A to fp8 e4m3 (OCP, via v_cvt_pk_fp8_f32 — R7-verified,
// absmax 2.4e-4). Q: row-major fp8 (byte g*8). A: packed for 16x16x32 fp8 B-op:
// per 16-col tile T, k-pair p in {0,1}: 1 KB region at T*2048 + p*1024; lane
// L = quad*16+e holds 16 B at L*16 = A[col=T*16+e][k=(2p)*32+quad*8..+7] ++
// A[col][k=(2p+1)*32+quad*8..+7]. 8 consecutive tiles (16 KB) = one LDS stage.
// Also zeroes d_out (harness re-poisons to 0xAA before every replay).
__global__ void cvt_kernel(const float* __restrict__ q, const float* __restrict__ a,
                           unsigned char* __restrict__ qp, unsigned char* __restrict__ ap,
                           float* __restrict__ out) {
    const int g = blockIdx.x * blockDim.x + threadIdx.x;   // 0 .. B*D/8-1
    if (g < 2) out[g] = 0.0f;

    float4 q0 = reinterpret_cast<const float4*>(q)[g * 2];
    float4 q1 = reinterpret_cast<const float4*>(q)[g * 2 + 1];
    float4 a0 = reinterpret_cast<const float4*>(a)[g * 2];
    float4 a1 = reinterpret_cast<const float4*>(a)[g * 2 + 1];

    int qw0 = __builtin_amdgcn_cvt_pk_fp8_f32(q0.x, q0.y, 0, false);
    qw0     = __builtin_amdgcn_cvt_pk_fp8_f32(q0.z, q0.w, qw0, true);
    int qw1 = __builtin_amdgcn_cvt_pk_fp8_f32(q1.x, q1.y, 0, false);
    qw1     = __builtin_amdgcn_cvt_pk_fp8_f32(q1.z, q1.w, qw1, true);
    int aw0 = __builtin_amdgcn_cvt_pk_fp8_f32(a0.x, a0.y, 0, false);
    aw0     = __builtin_amdgcn_cvt_pk_fp8_f32(a0.z, a0.w, aw0, true);
    int aw1 = __builtin_amdgcn_cvt_pk_fp8_f32(a1.x, a1.y, 0, false);
    aw1     = __builtin_amdgcn_cvt_pk_fp8_f32(a1.z, a1.w, aw1, true);

    // Q row-major fp8
    *reinterpret_cast<int2*>(qp + (size_t)g * 8) = make_int2(qw0, qw1);

    // A fragment-packed fp8
    const int col = g >> 4, sq = g & 15;       // k = sq*8 .. +7
    const int s = sq >> 2, quad = sq & 3;      // k-step of 32, quad within step
    const int T = col >> 4, e = col & 15;
    const size_t off = (size_t)T * 2048 + (size_t)(s >> 1) * 1024
                     + (size_t)(quad * 16 + e) * 16 + (size_t)(s & 1) * 8;
    *reinterpret_cast<int2*>(ap + off) = make_int2(aw0, aw1);
}

// Block (rg, cs): rows [rg*64,+64) over cols [cs*1024,+1024). 4 waves; wave w owns
// rows [rg*64 + w*16, +16); all waves sweep the same cols via LDS-shared B-tiles.
// == R9's verified structure with fp8 staging: 16 KB stage now covers 128 cols
// (vs 64 for bf16) -> LDS bytes/cell 16->8 AND barriers 16->8.
// Double-buffered LDS (2 x 16 KB); stage t+1 issued after the barrier publishing t.
// MFMA 16x16x32 fp8_fp8 (R7-verified lane mapping, absmax 2.4e-4):
//   A-op: lane holds A[m=lane&15][k=(lane>>4)*8+j] (8 B); B-op transposed same;
//   C/D : col=lane&15, row=(lane>>4)*4+reg.
// Sentinels: VGPR ~55, WRITE_SIZE ~1 MB, SQ_LDS_BANK_CONFLICT ~0.
__launch_bounds__(256, 4)
__global__ void mpl_part_kernel(const unsigned char* __restrict__ qp,
                                const unsigned char* __restrict__ ap,
                                const int* __restrict__ qids,
                                const float* __restrict__ ranks,
                                float* __restrict__ pden, float* __restrict__ pnum,
                                float* __restrict__ pmax, float* __restrict__ pmaxp) {
    __shared__ unsigned char smem[2 * 16384];   // 2 x 16 KB

    const int tid  = threadIdx.x;
    const int lane = tid & 63;
    const int wave = tid >> 6;               // 0..3
    const int rg   = blockIdx.x >> 3;        // 0..127
    const int cs   = blockIdx.x & 7;         // 0..7 (== XCD id under %8 dispatch)
    const int rowBase = rg * ROWS;
    const int quad = lane >> 4;              // 0..3
    const int l15  = lane & 15;

    // Q fragments: this wave's 16-row tile x 4 k-steps of 32 (8 VGPRs).
    long qfrag[4];
    {
        const unsigned char* qrow = qp + (size_t)(rowBase + wave * 16 + l15) * D_K + quad * 8;
        #pragma unroll
        for (int s = 0; s < 4; ++s)
            qfrag[s] = *reinterpret_cast<const long*>(qrow + s * 32);
    }

    int qidrow[4];
    #pragma unroll
    for (int r = 0; r < 4; ++r)
        qidrow[r] = qids[rowBase + wave * 16 + quad * 4 + r];

    float den[4], num[4], mxv[4], mxp[4];
    #pragma unroll
    for (int r = 0; r < 4; ++r) {
        den[r] = 0.f; num[r] = 0.f; mxv[r] = -INFINITY; mxp[r] = -INFINITY;
    }

    const float L2E = 1.4426950408889634f;   // log2(e)
    const float CB  = 64.0f;                 // fixed exponent bias; cancels in num/den
    const int colStart = cs * 1024;

    // Packed A bytes for this block's col strip: 64 tiles x 2 KB = 128 KB.
    const char* gstrip = (const char*)ap + (size_t)cs * 131072;
    const int   chunk  = wave * 4096;        // this wave's 4 KB of each 16 KB stage

    // Prologue: stage super-tile 0 into buffer 0.
    #pragma unroll
    for (int i = 0; i < 4; ++i)
        gl_lds16(gstrip + chunk + i * 1024 + lane * 16,
                 (char*)smem + chunk + i * 1024);
    __syncthreads();

    for (int t = 0; t < T_OUT; ++t) {
        const int cur = t & 1, nxt = cur ^ 1;
        // Stage t+1 (async; completes during this iteration's compute).
        if (t + 1 < T_OUT) {
            const char* gsrc = gstrip + (size_t)(t + 1) * 16384 + chunk;
            char*       ldst = (char*)smem + nxt * 16384 + chunk;
            #pragma unroll
            for (int i = 0; i < 4; ++i)
                gl_lds16(gsrc + i * 1024 + lane * 16, ldst + i * 1024);
        }

        // Compute from buffer cur: 8 sub-tiles of 16 cols x 4 k-steps.
        const unsigned char* lbase = smem + cur * 16384 + lane * 16;
        #pragma unroll
        for (int u = 0; u < 8; ++u) {
            lx2 b01 = *reinterpret_cast<const lx2*>(lbase + u * 2048);
            lx2 b23 = *reinterpret_cast<const lx2*>(lbase + u * 2048 + 1024);

            f32x4 acc = {0.f, 0.f, 0.f, 0.f};
            acc = __builtin_amdgcn_mfma_f32_16x16x32_fp8_fp8(qfrag[0], b01[0], acc, 0, 0, 0);
            acc = __builtin_amdgcn_mfma_f32_16x16x32_fp8_fp8(qfrag[1], b01[1], acc, 0, 0, 0);
            acc = __builtin_amdgcn_mfma_f32_16x16x32_fp8_fp8(qfrag[2], b23[0], acc, 0, 0, 0);
            acc = __builtin_amdgcn_mfma_f32_16x16x32_fp8_fp8(qfrag[3], b23[1], acc, 0, 0, 0);

            const int c  = colStart + t * 128 + u * 16 + l15;
            const int qc = qids[c];
            const float wc = 1.0f - 0.1f * ranks[c];
            #pragma unroll
            for (int r = 0; r < 4; ++r) {
                float sv = acc[r];
                float e  = __builtin_amdgcn_exp2f(fmaf(sv, L2E, -CB));
                bool pos = (qc == qidrow[r]);
                den[r] += e;
                num[r] = fmaf(pos ? wc : 0.0f, e, num[r]);
                mxv[r] = fmaxf(mxv[r], sv);
                mxp[r] = fmaxf(mxp[r], pos ? sv : -INFINITY);
            }
        }
        __syncthreads();   // reads of cur done + stage of nxt done
    }

    // Reduce across the 16 lanes of each quad (same rows, different cols).
    #pragma unroll
    for (int m = 1; m <= 8; m <<= 1) {
        #pragma unroll
        for (int r = 0; r < 4; ++r) {
            den[r] += __shfl_xor(den[r], m, 64);
            num[r] += __shfl_xor(num[r], m, 64);
            mxv[r]  = fmaxf(mxv[r], __shfl_xor(mxv[r], m, 64));
            mxp[r]  = fmaxf(mxp[r], __shfl_xor(mxp[r], m, 64));
        }
    }

    if (l15 == 0) {   // lanes 0,16,32,48: write 4 rows each (wave-exclusive rows)
        const int rb = cs * B_N + rowBase + wave * 16 + quad * 4;
        #pragma unroll
        for (int r = 0; r < 4; ++r) {
            pden[rb + r]  = den[r];
            pnum[rb + r]  = num[r];
            pmax[rb + r]  = mxv[r];
            pmaxp[rb + r] = mxp[r];
        }
    }
}

// Finalize: 32 blocks x 256 threads, one row per thread (coalesced partial reads),
// block-reduce, atomicAdd into d_out (zeroed by cvt_kernel).
__launch_bounds__(256, 4)
__global__ void fin_kernel(const float* __restrict__ pden, const float* __restrict__ pnum,
                           const float* __restrict__ pmax, const float* __restrict__ pmaxp,
                           float* __restrict__ out) {
    const int r = blockIdx.x * 256 + threadIdx.x;
    float d = 0.f, n = 0.f, mv = -INFINITY, mp = -INFINITY;
    #pragma unroll
    for (int cs = 0; cs < CSPLIT; ++cs) {
        d += pden[cs * B_N + r];
        n += pnum[cs * B_N + r];
        mv = fmaxf(mv, pmax[cs * B_N + r]);
        mp = fmaxf(mp, pmaxp[cs * B_N + r]);
    }
    float lsum = -logf(n / d + 1e-8f);
    float csum = (mp == mv) ? 1.0f : 0.0f;   // argmax col positive <=> pos-max == global max
    #pragma unroll
    for (int m = 1; m <= 32; m <<= 1) {
        lsum += __shfl_xor(lsum, m, 64);
        csum += __shfl_xor(csum, m, 64);
    }
    __shared__ float sl[4], sc[4];
    const int wave = threadIdx.x >> 6;
    if ((threadIdx.x & 63) == 0) { sl[wave] = lsum; sc[wave] = csum; }
    __syncthreads();
    if (threadIdx.x == 0) {
        float L = sl[0] + sl[1] + sl[2] + sl[3];
        float C = sc[0] + sc[1] + sc[2] + sc[3];
        atomicAdd(&out[0], L * (1.0f / B_N));
        atomicAdd(&out[1], C * (1.0f / B_N));
    }
}

extern "C" void kernel_launch(void* const* d_in, const int* in_sizes, int n_in,
                              void* d_out, int out_size, void* d_ws, size_t ws_size,
                              hipStream_t stream) {
    const float* q     = (const float*)d_in[0];
    const float* a     = (const float*)d_in[1];
    const int*   qids  = (const int*)d_in[2];
    const float* ranks = (const float*)d_in[3];
    float* out = (float*)d_out;

    unsigned char* qp = (unsigned char*)d_ws;                       // 1 MB fp8 Q (row-major)
    unsigned char* ap = qp + (size_t)B_N * D_K;                     // 1 MB fp8 A (packed)
    char* p = (char*)(ap + (size_t)B_N * D_K);
    float* pden  = (float*)p;                p += CSPLIT * B_N * sizeof(float);
    float* pnum  = (float*)p;                p += CSPLIT * B_N * sizeof(float);
    float* pmax  = (float*)p;                p += CSPLIT * B_N * sizeof(float);
    float* pmaxp = (float*)p;

    cvt_kernel<<<(B_N * D_K / 8) / 256, 256, 0, stream>>>(q, a, qp, ap, out);
    mpl_part_kernel<<<(B_N / ROWS) * CSPLIT, 256, 0, stream>>>(qp, ap, qids, ranks,
                                                               pden, pnum, pmax, pmaxp);
    fin_kernel<<<B_N / 256, 256, 0, stream>>>(pden, pnum, pmax, pmaxp, out);
}